// Round 1
// baseline (5578.074 us; speedup 1.0000x reference)
//
#include <hip/hip_runtime.h>
#include <math.h>

// ---------------------------------------------------------------------------
// VMD, T = 2^20, K = 3.  Frequency-domain iteration never materializes u:
//   u[k][t] = (f_hat[t] - lam[t]/2) * g_k(t),  g_k real.
// fftshift folded into (-1)^n input modulation; ifftshift into (-1)^n output.
// FFT = six-step 1024x1024: transpose, row-FFT(+twiddle), transpose, row-FFT,
// transpose.  All transposes 32x32 LDS tiles, fully coalesced.
// ---------------------------------------------------------------------------

#define TN        (1 << 20)
#define FALPHA    2000.0f
#define FTAU      1e-7f
#define FTOL      1e-6f
#define FEPS      1e-8f
#define FTWO_PI   6.28318530717958647692f
#define FINV_T    (1.0f / 1048576.0f)

__device__ __forceinline__ float2 cmulf(float2 a, float2 b) {
    return make_float2(a.x * b.x - a.y * b.y, a.x * b.y + a.y * b.x);
}
__device__ __forceinline__ float2 cisf(float a) {
    float s, c;
    sincosf(a, &s, &c);
    return make_float2(c, s);
}

// g_k(fr) for K=3 with neighbor coupling (stale omega, like the reference)
__device__ __forceinline__ void g3f(float fr, float om0, float om1, float om2,
                                    float& g0, float& g1, float& g2) {
    const float tau2 = FTAU * FTAU;
    float d0 = fr - om0; d0 *= d0;
    float d1 = fr - om1; d1 *= d1;
    float d2 = fr - om2; d2 *= d2;
    g0 = 1.0f / (1.0f + FALPHA * (d0 + d1 + tau2));
    g1 = 1.0f / (1.0f + FALPHA * (d0 + d1 + d2 + tau2));
    g2 = 1.0f / (1.0f + FALPHA * (d1 + d2 + tau2));
}

// ---------------------------------------------------------------------------
// init: zero both lambda buffers, seed omega history, reset flags/tickets
// ---------------------------------------------------------------------------
__global__ __launch_bounds__(256)
void k_init(float4* __restrict__ l0, float4* __restrict__ l1,
            const float* __restrict__ omega0,
            float* __restrict__ om_hist, float* __restrict__ oom,
            int* __restrict__ lam_idx, int* __restrict__ done,
            unsigned* __restrict__ tickets) {
    const int idx = blockIdx.x * 256 + threadIdx.x;
    const float4 z = make_float4(0.f, 0.f, 0.f, 0.f);
    if (idx < TN / 2) { l0[idx] = z; l1[idx] = z; }
    if (blockIdx.x == 0) {
        if (threadIdx.x < 50) tickets[threadIdx.x] = 0u;
        if (threadIdx.x < 3) {
            const float w = 0.5f * omega0[threadIdx.x];
            om_hist[threadIdx.x] = w;   // omega entering iteration 0
            oom[threadIdx.x] = w;
        }
        if (threadIdx.x == 0) { *lam_idx = 0; *done = 0; }
    }
}

// ---------------------------------------------------------------------------
// per-element VMD update (accumulates reduction terms into acc[8])
// acc: 0..2 = sum power_k, 3..5 = sum power_k*fr, 6 = |u-uprev|^2, 7 = |uprev|^2
// ---------------------------------------------------------------------------
__device__ __forceinline__ void vmd_point(
    float fr, float fx, float fy, float lax, float lay,
    float lbx, float lby, int check,
    float om0, float om1, float om2,
    float op0, float op1, float op2,
    float* acc, float& lnx, float& lny) {
    float cr = fx - 0.5f * lax;
    float ci = fy - 0.5f * lay;
    float g0, g1, g2;
    g3f(fr, om0, om1, om2, g0, g1, g2);
    float m2 = cr * cr + ci * ci;
    float q0 = m2 * g0 * g0, q1 = m2 * g1 * g1, q2 = m2 * g2 * g2;
    acc[0] += q0; acc[1] += q1; acc[2] += q2;
    acc[3] += q0 * fr; acc[4] += q1 * fr; acc[5] += q2 * fr;
    float gs = g0 + g1 + g2;
    lnx = lax + FTAU * (cr * gs - fx);
    lny = lay + FTAU * (ci * gs - fy);
    if (check) {
        float pr = fx - 0.5f * lbx;
        float pi = fy - 0.5f * lby;
        float h0, h1, h2;
        g3f(fr, op0, op1, op2, h0, h1, h2);
        float ax, ay, s = 0.f;
        ax = cr * g0 - pr * h0; ay = ci * g0 - pi * h0; s += ax * ax + ay * ay;
        ax = cr * g1 - pr * h1; ay = ci * g1 - pi * h1; s += ax * ax + ay * ay;
        ax = cr * g2 - pr * h2; ay = ci * g2 - pi * h2; s += ax * ax + ay * ay;
        acc[6] += s;
        acc[7] += (pr * pr + pi * pi) * (h0 * h0 + h1 * h1 + h2 * h2);
    }
}

// ---------------------------------------------------------------------------
// one VMD iteration: elementwise u/lam update + omega reductions.
// Last block (device-scope ticket) finalizes omega, conv check, done flag.
// ---------------------------------------------------------------------------
__global__ __launch_bounds__(256)
void k_iter(const float2* __restrict__ fhat, const float2* __restrict__ lamA,
            float2* __restrict__ lamB, float* __restrict__ partials,
            float* __restrict__ om_hist, float* __restrict__ oom,
            int* __restrict__ lam_idx, int* __restrict__ done,
            unsigned* __restrict__ tickets, int n, int check) {
    if (*done) return;   // frozen after convergence (uniform branch)

    const float om0 = om_hist[3 * n + 0];
    const float om1 = om_hist[3 * n + 1];
    const float om2 = om_hist[3 * n + 2];
    float op0 = 0.f, op1 = 0.f, op2 = 0.f;
    if (check) {
        op0 = om_hist[3 * (n - 1) + 0];
        op1 = om_hist[3 * (n - 1) + 1];
        op2 = om_hist[3 * (n - 1) + 2];
    }

    float acc[8];
#pragma unroll
    for (int v = 0; v < 8; ++v) acc[v] = 0.f;

    const float4* __restrict__ f4  = (const float4*)fhat;
    const float4* __restrict__ la4 = (const float4*)lamA;
    float4* __restrict__ lb4 = (float4*)lamB;

#pragma unroll
    for (int half = 0; half < 2; ++half) {
        const int vidx = blockIdx.x * 512 + half * 256 + threadIdx.x;
        float4 f  = f4[vidx];
        float4 la = la4[vidx];
        float4 lb = make_float4(0.f, 0.f, 0.f, 0.f);
        if (check) lb = lb4[vidx];          // lam_{n-2}, read before overwrite
        const int t0 = vidx * 2;
        float4 ln;
        {
            const float fr = (float)t0 * FINV_T - 0.5f;
            vmd_point(fr, f.x, f.y, la.x, la.y, lb.x, lb.y, check,
                      om0, om1, om2, op0, op1, op2, acc, ln.x, ln.y);
        }
        {
            const float fr = (float)(t0 + 1) * FINV_T - 0.5f;
            vmd_point(fr, f.z, f.w, la.z, la.w, lb.z, lb.w, check,
                      om0, om1, om2, op0, op1, op2, acc, ln.z, ln.w);
        }
        lb4[vidx] = ln;                     // lam_n
    }

    // block reduction (wave shuffle + LDS across 4 waves)
    const int lane = threadIdx.x & 63;
    const int wid  = threadIdx.x >> 6;
#pragma unroll
    for (int off = 32; off > 0; off >>= 1) {
#pragma unroll
        for (int v = 0; v < 8; ++v) acc[v] += __shfl_down(acc[v], off);
    }
    __shared__ float wsum[4][8];
    if (lane == 0) {
#pragma unroll
        for (int v = 0; v < 8; ++v) wsum[wid][v] = acc[v];
    }
    __syncthreads();
    if (threadIdx.x == 0) {
#pragma unroll
        for (int v = 0; v < 8; ++v)
            partials[v * 1024 + blockIdx.x] =
                wsum[0][v] + wsum[1][v] + wsum[2][v] + wsum[3][v];
    }
    __threadfence();
    __shared__ int amLast;
    if (threadIdx.x == 0)
        amLast = (atomicAdd(&tickets[n], 1u) == gridDim.x - 1);
    __syncthreads();
    if (!amLast) return;
    __threadfence();

    // last block: deterministic reduction of 1024 partials in double
    double dacc[8];
#pragma unroll
    for (int v = 0; v < 8; ++v) dacc[v] = 0.0;
    for (int b = threadIdx.x; b < 1024; b += 256) {
#pragma unroll
        for (int v = 0; v < 8; ++v) dacc[v] += (double)partials[v * 1024 + b];
    }
#pragma unroll
    for (int off = 32; off > 0; off >>= 1) {
#pragma unroll
        for (int v = 0; v < 8; ++v) dacc[v] += __shfl_down(dacc[v], off);
    }
    __shared__ double dred[4][8];
    if (lane == 0) {
#pragma unroll
        for (int v = 0; v < 8; ++v) dred[wid][v] = dacc[v];
    }
    __syncthreads();
    if (threadIdx.x == 0) {
        double s[8];
#pragma unroll
        for (int v = 0; v < 8; ++v)
            s[v] = dred[0][v] + dred[1][v] + dred[2][v] + dred[3][v];
        const float on0 = (float)(s[3] / (s[0] + (double)FEPS));
        const float on1 = (float)(s[4] / (s[1] + (double)FEPS));
        const float on2 = (float)(s[5] / (s[2] + (double)FEPS));
        // record state that generates u_n (entry lam/omega) -> output snapshot
        oom[0] = om0; oom[1] = om1; oom[2] = om2;
        *lam_idx = (n & 1);
        om_hist[3 * (n + 1) + 0] = on0;
        om_hist[3 * (n + 1) + 1] = on1;
        om_hist[3 * (n + 1) + 2] = on2;
        if (check) {
            const double ud = s[6] / (s[7] + (double)FEPS);
            const float od = (fabsf(on0 - on2) + fabsf(on1 - on0) +
                              fabsf(on2 - on1)) * (1.0f / 3.0f);
            if (ud < (double)FTOL && od < FTOL) *done = 1;
        }
    }
}

// ---------------------------------------------------------------------------
// 1024-point Stockham radix-4 FFT per row (contiguous), 256 thr/block.
// dir = -1 forward / +1 inverse.  do_tw: multiply by e^{dir*2πi*row*col/2^20}.
// ---------------------------------------------------------------------------
__global__ __launch_bounds__(256)
void k_fft1024(const float2* __restrict__ in, float2* __restrict__ out,
               float dir, int do_tw) {
    __shared__ float2 bufA[1024];
    __shared__ float2 bufB[1024];
    const int row  = blockIdx.x;
    const int rowm = row & 1023;
    const float2* __restrict__ rin  = in  + (size_t)row * 1024;
    float2* __restrict__ rout = out + (size_t)row * 1024;
    const int t = threadIdx.x;
#pragma unroll
    for (int r = 0; r < 4; ++r) bufA[t + 256 * r] = rin[t + 256 * r];
    __syncthreads();

    float2* src = bufA;
    float2* dst = bufB;
    int Ns = 1;
#pragma unroll
    for (int s = 0; s < 5; ++s) {
        const int jm = t & (Ns - 1);
        float2 v0 = src[t], v1 = src[t + 256], v2 = src[t + 512], v3 = src[t + 768];
        const float a = dir * (FTWO_PI * 0.25f) * ((float)jm / (float)Ns);
        float2 w1 = cisf(a);
        float2 w2 = cmulf(w1, w1);
        float2 w3 = cmulf(w2, w1);
        v1 = cmulf(v1, w1); v2 = cmulf(v2, w2); v3 = cmulf(v3, w3);
        float2 s0 = make_float2(v0.x + v2.x, v0.y + v2.y);
        float2 s1 = make_float2(v0.x - v2.x, v0.y - v2.y);
        float2 s2 = make_float2(v1.x + v3.x, v1.y + v3.y);
        float2 s3 = make_float2(v1.x - v3.x, v1.y - v3.y);
        float2 s3i = make_float2(-dir * s3.y, dir * s3.x);  // dir*i * s3
        const int base = ((t - jm) << 2) + jm;
        dst[base]          = make_float2(s0.x + s2.x, s0.y + s2.y);
        dst[base + Ns]     = make_float2(s1.x + s3i.x, s1.y + s3i.y);
        dst[base + 2 * Ns] = make_float2(s0.x - s2.x, s0.y - s2.y);
        dst[base + 3 * Ns] = make_float2(s1.x - s3i.x, s1.y - s3i.y);
        __syncthreads();
        float2* tmp = src; src = dst; dst = tmp;
        Ns <<= 2;
    }
#pragma unroll
    for (int r = 0; r < 4; ++r) {
        const int c = t + 256 * r;
        float2 xv = src[c];
        if (do_tw) {
            const unsigned p = ((unsigned)rowm * (unsigned)c) & 1048575u;
            const float a = dir * (FTWO_PI * FINV_T) * (float)p;
            xv = cmulf(xv, cisf(a));
        }
        rout[c] = xv;
    }
}

// ---------------------------------------------------------------------------
// transposes (32x32 tiles, block (32,8)); grid z = batch
// ---------------------------------------------------------------------------
__global__ __launch_bounds__(256)
void k_tr_c2c(const float2* __restrict__ in, float2* __restrict__ out) {
    __shared__ float2 tile[32][33];
    const size_t zo = (size_t)blockIdx.z * TN;
    const int bx = blockIdx.x * 32, by = blockIdx.y * 32;
    const int tx = threadIdx.x, ty = threadIdx.y;
#pragma unroll
    for (int j = 0; j < 32; j += 8)
        tile[ty + j][tx] = in[zo + (size_t)(by + ty + j) * 1024 + bx + tx];
    __syncthreads();
#pragma unroll
    for (int j = 0; j < 32; j += 8)
        out[zo + (size_t)(bx + ty + j) * 1024 + by + tx] = tile[tx][ty + j];
}

// forward input: y = (-1)^n * x  (sign by output row = n2), real -> complex
__global__ __launch_bounds__(256)
void k_tr_fwd_in(const float* __restrict__ in, float2* __restrict__ out) {
    __shared__ float tile[32][33];
    const int bx = blockIdx.x * 32, by = blockIdx.y * 32;
    const int tx = threadIdx.x, ty = threadIdx.y;
#pragma unroll
    for (int j = 0; j < 32; j += 8)
        tile[ty + j][tx] = in[(size_t)(by + ty + j) * 1024 + bx + tx];
    __syncthreads();
#pragma unroll
    for (int j = 0; j < 32; j += 8) {
        const int r = bx + ty + j;
        float v = tile[tx][ty + j];
        v = (r & 1) ? -v : v;
        out[(size_t)r * 1024 + by + tx] = make_float2(v, 0.0f);
    }
}

// inverse input: compute u_k = (f_hat - lam/2)*g_k on the fly, write transposed
__global__ __launch_bounds__(256)
void k_tr_u_in(const float2* __restrict__ fhat,
               const float2* __restrict__ lam0,
               const float2* __restrict__ lam1,
               const int* __restrict__ lam_idx,
               const float* __restrict__ oom,
               float2* __restrict__ out, int kstart, int kcount) {
    __shared__ float2 tu[3][32][33];
    const float2* __restrict__ lam = (*lam_idx) ? lam1 : lam0;
    const float om0 = oom[0], om1 = oom[1], om2 = oom[2];
    const int bx = blockIdx.x * 32, by = blockIdx.y * 32;
    const int tx = threadIdx.x, ty = threadIdx.y;
#pragma unroll
    for (int j = 0; j < 32; j += 8) {
        const int row = by + ty + j, col = bx + tx;
        const int t = row * 1024 + col;
        const float2 f  = fhat[t];
        const float2 la = lam[t];
        const float cr = f.x - 0.5f * la.x;
        const float ci = f.y - 0.5f * la.y;
        const float fr = (float)t * FINV_T - 0.5f;
        float g0, g1, g2;
        g3f(fr, om0, om1, om2, g0, g1, g2);
        const float gg[3] = {g0, g1, g2};
        for (int kk = 0; kk < kcount; ++kk) {
            const float g = gg[kstart + kk];
            tu[kk][ty + j][tx] = make_float2(cr * g, ci * g);
        }
    }
    __syncthreads();
#pragma unroll
    for (int j = 0; j < 32; j += 8)
        for (int kk = 0; kk < kcount; ++kk)
            out[(size_t)kk * TN + (size_t)(bx + ty + j) * 1024 + by + tx] =
                tu[kk][tx][ty + j];
}

// inverse output: imf = (-1)^{n2} * (1/N) * Re(R^T)  (sign by output column)
__global__ __launch_bounds__(256)
void k_tr_out(const float2* __restrict__ in, float* __restrict__ out) {
    __shared__ float2 tile[32][33];
    const size_t zo = (size_t)blockIdx.z * TN;
    const int bx = blockIdx.x * 32, by = blockIdx.y * 32;
    const int tx = threadIdx.x, ty = threadIdx.y;
#pragma unroll
    for (int j = 0; j < 32; j += 8)
        tile[ty + j][tx] = in[zo + (size_t)(by + ty + j) * 1024 + bx + tx];
    __syncthreads();
    const int c = by + tx;
    const float sgn = (c & 1) ? -FINV_T : FINV_T;
#pragma unroll
    for (int j = 0; j < 32; j += 8) {
        const int r = bx + ty + j;
        out[zo + (size_t)r * 1024 + c] = tile[tx][ty + j].x * sgn;
    }
}

// ---------------------------------------------------------------------------
extern "C" void kernel_launch(void* const* d_in, const int* in_sizes, int n_in,
                              void* d_out, int out_size, void* d_ws, size_t ws_size,
                              hipStream_t stream) {
    (void)in_sizes; (void)n_in; (void)out_size;
    const float* x      = (const float*)d_in[0];
    const float* omega0 = (const float*)d_in[1];
    float* outp = (float*)d_out;
    char* ws = (char*)d_ws;

    const size_t MB = (size_t)1 << 20;
    float2* fhat = (float2*)(ws);               // 8 MB
    float2* lam0 = (float2*)(ws + 8 * MB);      // 8 MB
    float2* lam1 = (float2*)(ws + 16 * MB);     // 8 MB
    float*  partials = (float*)(ws + 24 * MB);  // 32 KB
    float*  om_hist  = (float*)(ws + 24 * MB + 64 * 1024);  // 51*3 floats
    float*  oom      = om_hist + 51 * 3;
    int*    lam_idx  = (int*)(oom + 3);
    int*    done     = lam_idx + 1;
    unsigned* tickets = (unsigned*)(done + 1);  // 50
    const bool batch3 = ws_size >= 74 * MB;
    float2* sA = (float2*)(ws + 25 * MB);                       // 8 or 24 MB
    float2* sB = batch3 ? (float2*)(ws + 49 * MB)
                        : (float2*)(ws + 33 * MB);

    dim3 tb(32, 8);
    dim3 tg(32, 32);

    k_init<<<2048, 256, 0, stream>>>((float4*)lam0, (float4*)lam1, omega0,
                                     om_hist, oom, lam_idx, done, tickets);

    // forward FFT of (-1)^n * x  ->  f_hat (fftshifted spectrum)
    k_tr_fwd_in<<<tg, tb, 0, stream>>>(x, sA);
    k_fft1024<<<1024, 256, 0, stream>>>(sA, sB, -1.0f, 1);
    k_tr_c2c<<<tg, tb, 0, stream>>>(sB, sA);
    k_fft1024<<<1024, 256, 0, stream>>>(sA, sB, -1.0f, 0);
    k_tr_c2c<<<tg, tb, 0, stream>>>(sB, fhat);

    // 50 VMD iterations (lam ping-pong; u never materialized)
    for (int n = 0; n < 50; ++n) {
        float2* la = (n & 1) ? lam1 : lam0;   // lam_{n-1}
        float2* lb = (n & 1) ? lam0 : lam1;   // lam_{n-2} in, lam_n out
        const int check = (n > 0 && (n % 10) == 0) ? 1 : 0;
        k_iter<<<1024, 256, 0, stream>>>(fhat, la, lb, partials, om_hist, oom,
                                         lam_idx, done, tickets, n, check);
    }

    // inverse FFTs of u_k, output (-1)^n * Re(ifft)/N
    if (batch3) {
        k_tr_u_in<<<tg, tb, 0, stream>>>(fhat, lam0, lam1, lam_idx, oom, sA, 0, 3);
        k_fft1024<<<3072, 256, 0, stream>>>(sA, sB, 1.0f, 1);
        k_tr_c2c<<<dim3(32, 32, 3), tb, 0, stream>>>(sB, sA);
        k_fft1024<<<3072, 256, 0, stream>>>(sA, sB, 1.0f, 0);
        k_tr_out<<<dim3(32, 32, 3), tb, 0, stream>>>(sB, outp);
    } else {
        for (int k = 0; k < 3; ++k) {
            k_tr_u_in<<<tg, tb, 0, stream>>>(fhat, lam0, lam1, lam_idx, oom, sA, k, 1);
            k_fft1024<<<1024, 256, 0, stream>>>(sA, sB, 1.0f, 1);
            k_tr_c2c<<<tg, tb, 0, stream>>>(sB, sA);
            k_fft1024<<<1024, 256, 0, stream>>>(sA, sB, 1.0f, 0);
            k_tr_out<<<tg, tb, 0, stream>>>(sB, outp + (size_t)k * TN);
        }
    }
}

// Round 2
// 754.678 us; speedup vs baseline: 7.3913x; 7.3913x over previous
//
#include <hip/hip_runtime.h>
#include <math.h>

// ---------------------------------------------------------------------------
// VMD, T = 2^20, K = 3.  u[k][t] = (f_hat[t] - lam[t]/2) * g_k(t), g_k real:
// u is never materialized.  fftshift folded into (-1)^n input modulation;
// ifftshift into (-1)^n output sign.
//
// Round-2 restructure: NO intra-kernel device-scope sync (the round-1 ticket +
// __threadfence forced per-block bulk L2 writebacks -> 127us/iter).  Cross-
// block reduction now crosses a KERNEL BOUNDARY: iteration n writes per-block
// partials with plain stores; iteration n+1 redundantly reduces them in every
// block (32 KB, L2-broadcast, deterministic).  The iteration phase runs in the
// six-step FFT's digit-scrambled order (freqs via digit swap), deleting two
// transpose passes and fusing u-compute into the first inverse-FFT kernel.
// ---------------------------------------------------------------------------

#define TN        (1 << 20)
#define NB        1024        // k_iter grid (partials stride)
#define FALPHA    2000.0f
#define FTAU      1e-7f
#define FTOL      1e-6f
#define FEPS      1e-8f
#define FTWO_PI   6.28318530717958647692f
#define FINV_T    (1.0f / 1048576.0f)

__device__ __forceinline__ float2 cmulf(float2 a, float2 b) {
    return make_float2(a.x * b.x - a.y * b.y, a.x * b.y + a.y * b.x);
}
__device__ __forceinline__ float2 cisf(float a) {
    float s, c;
    sincosf(a, &s, &c);
    return make_float2(c, s);
}
// scrambled storage index q -> true (fftshifted) frequency index t
__device__ __forceinline__ int descramble(int q) {
    return ((q & 1023) << 10) | (q >> 10);
}

// g_k(fr) for K=3 with neighbor coupling (stale omega, like the reference)
__device__ __forceinline__ void g3f(float fr, float om0, float om1, float om2,
                                    float& g0, float& g1, float& g2) {
    const float tau2 = FTAU * FTAU;
    float d0 = fr - om0; d0 *= d0;
    float d1 = fr - om1; d1 *= d1;
    float d2 = fr - om2; d2 *= d2;
    g0 = 1.0f / (1.0f + FALPHA * (d0 + d1 + tau2));
    g1 = 1.0f / (1.0f + FALPHA * (d0 + d1 + d2 + tau2));
    g2 = 1.0f / (1.0f + FALPHA * (d1 + d2 + tau2));
}

// ---------------------------------------------------------------------------
// init: zero both lambda buffers, seed omega/state (ws is re-poisoned to 0xAA
// before every timed launch, so everything must be re-initialized here)
// ---------------------------------------------------------------------------
__global__ __launch_bounds__(256)
void k_init(float4* __restrict__ l0, float4* __restrict__ l1,
            const float* __restrict__ omega0,
            float* __restrict__ om_hist, float* __restrict__ oom,
            int* __restrict__ lam_idx, int* __restrict__ done) {
    const int idx = blockIdx.x * 256 + threadIdx.x;
    const float4 z = make_float4(0.f, 0.f, 0.f, 0.f);
    if (idx < TN / 2) { l0[idx] = z; l1[idx] = z; }
    if (blockIdx.x == 0) {
        if (threadIdx.x < 3) {
            const float w = 0.5f * omega0[threadIdx.x];
            om_hist[threadIdx.x] = w;   // omega entering iteration 0
            oom[threadIdx.x] = w;
        }
        if (threadIdx.x == 0) { *lam_idx = 0; *done = 0; }
    }
}

// ---------------------------------------------------------------------------
// per-element VMD update (accumulates reduction terms into acc[8])
// acc: 0..2 = sum power_k, 3..5 = sum power_k*fr, 6 = |u-uprev|^2, 7 = |uprev|^2
// ---------------------------------------------------------------------------
__device__ __forceinline__ void vmd_point(
    float fr, float fx, float fy, float lax, float lay,
    float lbx, float lby, int check,
    float om0, float om1, float om2,
    float op0, float op1, float op2,
    float* acc, float& lnx, float& lny) {
    float cr = fx - 0.5f * lax;
    float ci = fy - 0.5f * lay;
    float g0, g1, g2;
    g3f(fr, om0, om1, om2, g0, g1, g2);
    float m2 = cr * cr + ci * ci;
    float q0 = m2 * g0 * g0, q1 = m2 * g1 * g1, q2 = m2 * g2 * g2;
    acc[0] += q0; acc[1] += q1; acc[2] += q2;
    acc[3] += q0 * fr; acc[4] += q1 * fr; acc[5] += q2 * fr;
    float gs = g0 + g1 + g2;
    lnx = lax + FTAU * (cr * gs - fx);
    lny = lay + FTAU * (ci * gs - fy);
    if (check) {
        float pr = fx - 0.5f * lbx;
        float pi = fy - 0.5f * lby;
        float h0, h1, h2;
        g3f(fr, op0, op1, op2, h0, h1, h2);
        float ax, ay, s = 0.f;
        ax = cr * g0 - pr * h0; ay = ci * g0 - pi * h0; s += ax * ax + ay * ay;
        ax = cr * g1 - pr * h1; ay = ci * g1 - pi * h1; s += ax * ax + ay * ay;
        ax = cr * g2 - pr * h2; ay = ci * g2 - pi * h2; s += ax * ax + ay * ay;
        acc[6] += s;
        acc[7] += (pr * pr + pi * pi) * (h0 * h0 + h1 * h1 + h2 * h2);
    }
}

// ---------------------------------------------------------------------------
// one VMD iteration.  Reads previous iteration's partials (kernel-boundary
// visibility), redundantly reduces them in every block -> omega for this step
// (+ convergence decision at n=11/21/31/41).  Then elementwise lam update and
// new per-block partials.  No fences, no atomics.
// ---------------------------------------------------------------------------
__global__ __launch_bounds__(256)
void k_iter(const float2* __restrict__ fhat, const float2* __restrict__ lamA,
            float2* __restrict__ lamB,
            const float* __restrict__ pPrev, float* __restrict__ pCur,
            float* __restrict__ om_hist, float* __restrict__ oom,
            int* __restrict__ lam_idx, int* __restrict__ done,
            int n, int check, int convEval) {
    if (*done) return;   // frozen (set at least one kernel earlier)

    const int lane = threadIdx.x & 63;
    const int wid  = threadIdx.x >> 6;

    float om0, om1, om2;
    if (n == 0) {
        om0 = om_hist[0]; om1 = om_hist[1]; om2 = om_hist[2];
    } else {
        // redundant (identical in every block) reduction of 8x1024 partials
        double d[8];
#pragma unroll
        for (int v = 0; v < 8; ++v) d[v] = 0.0;
        for (int b = threadIdx.x; b < NB; b += 256) {
#pragma unroll
            for (int v = 0; v < 8; ++v) d[v] += (double)pPrev[v * NB + b];
        }
#pragma unroll
        for (int off = 32; off > 0; off >>= 1) {
#pragma unroll
            for (int v = 0; v < 8; ++v) d[v] += __shfl_down(d[v], off);
        }
        __shared__ double dred[4][8];
        if (lane == 0) {
#pragma unroll
            for (int v = 0; v < 8; ++v) dred[wid][v] = d[v];
        }
        __syncthreads();
        double s[8];
#pragma unroll
        for (int v = 0; v < 8; ++v)
            s[v] = dred[0][v] + dred[1][v] + dred[2][v] + dred[3][v];
        om0 = (float)(s[3] / (s[0] + (double)FEPS));
        om1 = (float)(s[4] / (s[1] + (double)FEPS));
        om2 = (float)(s[5] / (s[2] + (double)FEPS));
        if (convEval) {   // previous iteration was a %10 check
            const double ud = s[6] / (s[7] + (double)FEPS);
            const float od = (fabsf(om0 - om2) + fabsf(om1 - om0) +
                              fabsf(om2 - om1)) * (1.0f / 3.0f);
            if (ud < (double)FTOL && od < FTOL) {   // uniform across all blocks
                if (blockIdx.x == 0 && threadIdx.x == 0) *done = 1;
                return;
            }
        }
        __syncthreads();   // dred not reused, but keep lifetimes clean
    }

    float op0 = 0.f, op1 = 0.f, op2 = 0.f;
    if (check) {   // omega that generated u_{n-1}
        op0 = om_hist[3 * (n - 1) + 0];
        op1 = om_hist[3 * (n - 1) + 1];
        op2 = om_hist[3 * (n - 1) + 2];
    }

    float acc[8];
#pragma unroll
    for (int v = 0; v < 8; ++v) acc[v] = 0.f;

    const float4* __restrict__ f4  = (const float4*)fhat;
    const float4* __restrict__ la4 = (const float4*)lamA;
    float4* __restrict__ lb4 = (float4*)lamB;

#pragma unroll
    for (int half = 0; half < 2; ++half) {
        const int vidx = blockIdx.x * 512 + half * 256 + threadIdx.x;
        float4 f  = f4[vidx];
        float4 la = la4[vidx];
        float4 lb = make_float4(0.f, 0.f, 0.f, 0.f);
        if (check) lb = lb4[vidx];          // lam_{n-2}, read before overwrite
        const int q0 = vidx * 2;
        float4 ln;
        {
            const float fr = (float)descramble(q0) * FINV_T - 0.5f;
            vmd_point(fr, f.x, f.y, la.x, la.y, lb.x, lb.y, check,
                      om0, om1, om2, op0, op1, op2, acc, ln.x, ln.y);
        }
        {
            const float fr = (float)descramble(q0 + 1) * FINV_T - 0.5f;
            vmd_point(fr, f.z, f.w, la.z, la.w, lb.z, lb.w, check,
                      om0, om1, om2, op0, op1, op2, acc, ln.z, ln.w);
        }
        lb4[vidx] = ln;                     // lam_n
    }

    // per-block reduction of acc -> pCur (plain stores; next kernel reads)
#pragma unroll
    for (int off = 32; off > 0; off >>= 1) {
#pragma unroll
        for (int v = 0; v < 8; ++v) acc[v] += __shfl_down(acc[v], off);
    }
    __shared__ float wsum[4][8];
    if (lane == 0) {
#pragma unroll
        for (int v = 0; v < 8; ++v) wsum[wid][v] = acc[v];
    }
    __syncthreads();
    if (threadIdx.x == 0) {
#pragma unroll
        for (int v = 0; v < 8; ++v)
            pCur[v * NB + blockIdx.x] =
                wsum[0][v] + wsum[1][v] + wsum[2][v] + wsum[3][v];
    }
    // bookkeeping for later kernels (identical values in every block)
    if (blockIdx.x == 0 && threadIdx.x == 0) {
        om_hist[3 * n + 0] = om0;
        om_hist[3 * n + 1] = om1;
        om_hist[3 * n + 2] = om2;
        oom[0] = om0; oom[1] = om1; oom[2] = om2;  // omega generating u_n
        *lam_idx = (n & 1);                        // buffer holding lam_{n-1}
    }
}

// ---------------------------------------------------------------------------
// 1024-point Stockham radix-4 stages in LDS (caller loads bufA, then syncs)
// ---------------------------------------------------------------------------
__device__ __forceinline__ float2* fft1024_stages(float2* bufA, float2* bufB,
                                                  int t, float dir) {
    float2* src = bufA;
    float2* dst = bufB;
    int Ns = 1;
#pragma unroll
    for (int s = 0; s < 5; ++s) {
        const int jm = t & (Ns - 1);
        float2 v0 = src[t], v1 = src[t + 256], v2 = src[t + 512], v3 = src[t + 768];
        const float a = dir * (FTWO_PI * 0.25f) * ((float)jm / (float)Ns);
        float2 w1 = cisf(a);
        float2 w2 = cmulf(w1, w1);
        float2 w3 = cmulf(w2, w1);
        v1 = cmulf(v1, w1); v2 = cmulf(v2, w2); v3 = cmulf(v3, w3);
        float2 s0 = make_float2(v0.x + v2.x, v0.y + v2.y);
        float2 s1 = make_float2(v0.x - v2.x, v0.y - v2.y);
        float2 s2 = make_float2(v1.x + v3.x, v1.y + v3.y);
        float2 s3 = make_float2(v1.x - v3.x, v1.y - v3.y);
        float2 s3i = make_float2(-dir * s3.y, dir * s3.x);  // dir*i * s3
        const int base = ((t - jm) << 2) + jm;
        dst[base]          = make_float2(s0.x + s2.x, s0.y + s2.y);
        dst[base + Ns]     = make_float2(s1.x + s3i.x, s1.y + s3i.y);
        dst[base + 2 * Ns] = make_float2(s0.x - s2.x, s0.y - s2.y);
        dst[base + 3 * Ns] = make_float2(s1.x - s3i.x, s1.y - s3i.y);
        __syncthreads();
        float2* tmp = src; src = dst; dst = tmp;
        Ns <<= 2;
    }
    return src;
}

// generic row FFT: dir=-1 fwd / +1 inv; do_tw: * e^{dir*2pi*i*row*col/2^20}
__global__ __launch_bounds__(256)
void k_fft1024(const float2* __restrict__ in, float2* __restrict__ out,
               float dir, int do_tw) {
    __shared__ float2 bufA[1024];
    __shared__ float2 bufB[1024];
    const int row  = blockIdx.x;
    const int rowm = row & 1023;
    const float2* __restrict__ rin  = in  + (size_t)row * 1024;
    float2* __restrict__ rout = out + (size_t)row * 1024;
    const int t = threadIdx.x;
#pragma unroll
    for (int r = 0; r < 4; ++r) bufA[t + 256 * r] = rin[t + 256 * r];
    __syncthreads();
    float2* src = fft1024_stages(bufA, bufB, t, dir);
#pragma unroll
    for (int r = 0; r < 4; ++r) {
        const int c = t + 256 * r;
        float2 xv = src[c];
        if (do_tw) {
            const unsigned p = ((unsigned)rowm * (unsigned)c) & 1048575u;
            xv = cmulf(xv, cisf(dir * (FTWO_PI * FINV_T) * (float)p));
        }
        rout[c] = xv;
    }
}

// first inverse-FFT pass with u-compute fused into the load stage.
// Scrambled row `row` of fhat/lam IS the k2-row the inverse six-step needs.
__global__ __launch_bounds__(256)
void k_fftu(const float2* __restrict__ fhat,
            const float2* __restrict__ lam0, const float2* __restrict__ lam1,
            const int* __restrict__ lam_idx, const float* __restrict__ oom,
            float2* __restrict__ out, int kbase) {
    __shared__ float2 bufA[1024];
    __shared__ float2 bufB[1024];
    const int row = blockIdx.x & 1023;
    const int z   = blockIdx.x >> 10;
    const int kk  = kbase + z;
    const float2* __restrict__ lam = (*lam_idx) ? lam1 : lam0;
    const float om0 = oom[0], om1 = oom[1], om2 = oom[2];
    const float2* __restrict__ frow = fhat + (size_t)row * 1024;
    const float2* __restrict__ lrow = lam  + (size_t)row * 1024;
    const int t = threadIdx.x;
#pragma unroll
    for (int r = 0; r < 4; ++r) {
        const int c = t + 256 * r;
        const float2 f  = frow[c];
        const float2 la = lrow[c];
        const float cr = f.x - 0.5f * la.x;
        const float ci = f.y - 0.5f * la.y;
        const float fr = (float)((c << 10) | row) * FINV_T - 0.5f;
        float g0, g1, g2;
        g3f(fr, om0, om1, om2, g0, g1, g2);
        const float g = (kk == 0) ? g0 : ((kk == 1) ? g1 : g2);
        bufA[c] = make_float2(cr * g, ci * g);
    }
    __syncthreads();
    float2* src = fft1024_stages(bufA, bufB, t, 1.0f);
    float2* __restrict__ rout = out + (size_t)z * TN + (size_t)row * 1024;
#pragma unroll
    for (int r = 0; r < 4; ++r) {
        const int c = t + 256 * r;
        const unsigned p = ((unsigned)row * (unsigned)c) & 1048575u;
        rout[c] = cmulf(src[c], cisf((FTWO_PI * FINV_T) * (float)p));
    }
}

// ---------------------------------------------------------------------------
// transposes (32x32 LDS tiles, block (32,8)); grid z = batch
// ---------------------------------------------------------------------------
__global__ __launch_bounds__(256)
void k_tr_c2c(const float2* __restrict__ in, float2* __restrict__ out) {
    __shared__ float2 tile[32][33];
    const size_t zo = (size_t)blockIdx.z * TN;
    const int bx = blockIdx.x * 32, by = blockIdx.y * 32;
    const int tx = threadIdx.x, ty = threadIdx.y;
#pragma unroll
    for (int j = 0; j < 32; j += 8)
        tile[ty + j][tx] = in[zo + (size_t)(by + ty + j) * 1024 + bx + tx];
    __syncthreads();
#pragma unroll
    for (int j = 0; j < 32; j += 8)
        out[zo + (size_t)(bx + ty + j) * 1024 + by + tx] = tile[tx][ty + j];
}

// forward input: y = (-1)^n * x, transposed, real -> complex
__global__ __launch_bounds__(256)
void k_tr_fwd_in(const float* __restrict__ in, float2* __restrict__ out) {
    __shared__ float tile[32][33];
    const int bx = blockIdx.x * 32, by = blockIdx.y * 32;
    const int tx = threadIdx.x, ty = threadIdx.y;
#pragma unroll
    for (int j = 0; j < 32; j += 8)
        tile[ty + j][tx] = in[(size_t)(by + ty + j) * 1024 + bx + tx];
    __syncthreads();
#pragma unroll
    for (int j = 0; j < 32; j += 8) {
        const int r = bx + ty + j;
        float v = tile[tx][ty + j];
        v = (r & 1) ? -v : v;
        out[(size_t)r * 1024 + by + tx] = make_float2(v, 0.0f);
    }
}

// inverse output: imf = (-1)^n * (1/N) * Re(.), transposed store
__global__ __launch_bounds__(256)
void k_tr_out(const float2* __restrict__ in, float* __restrict__ out) {
    __shared__ float2 tile[32][33];
    const size_t zo = (size_t)blockIdx.z * TN;
    const int bx = blockIdx.x * 32, by = blockIdx.y * 32;
    const int tx = threadIdx.x, ty = threadIdx.y;
#pragma unroll
    for (int j = 0; j < 32; j += 8)
        tile[ty + j][tx] = in[zo + (size_t)(by + ty + j) * 1024 + bx + tx];
    __syncthreads();
    const int c = by + tx;
    const float sgn = (c & 1) ? -FINV_T : FINV_T;
#pragma unroll
    for (int j = 0; j < 32; j += 8) {
        const int r = bx + ty + j;
        out[zo + (size_t)r * 1024 + c] = tile[tx][ty + j].x * sgn;
    }
}

// ---------------------------------------------------------------------------
extern "C" void kernel_launch(void* const* d_in, const int* in_sizes, int n_in,
                              void* d_out, int out_size, void* d_ws, size_t ws_size,
                              hipStream_t stream) {
    (void)in_sizes; (void)n_in; (void)out_size;
    const float* x      = (const float*)d_in[0];
    const float* omega0 = (const float*)d_in[1];
    float* outp = (float*)d_out;
    char* ws = (char*)d_ws;

    const size_t MB = (size_t)1 << 20;
    float2* fhat = (float2*)(ws);               // 8 MB  (scrambled order)
    float2* lam0 = (float2*)(ws + 8 * MB);      // 8 MB
    float2* lam1 = (float2*)(ws + 16 * MB);     // 8 MB
    float*  partials = (float*)(ws + 24 * MB);  // 2 bufs x 8*NB floats = 64 KB
    float*  om_hist  = (float*)(ws + 24 * MB + 64 * 1024);  // 50*3 floats
    float*  oom      = om_hist + 50 * 3;
    int*    lam_idx  = (int*)(oom + 3);
    int*    done     = lam_idx + 1;
    const bool batch3 = ws_size >= 74 * MB;
    float2* sA = (float2*)(ws + 25 * MB);                       // 8 or 24 MB
    float2* sB = batch3 ? (float2*)(ws + 49 * MB)
                        : (float2*)(ws + 33 * MB);

    dim3 tb(32, 8);
    dim3 tg(32, 32);

    k_init<<<2048, 256, 0, stream>>>((float4*)lam0, (float4*)lam1, omega0,
                                     om_hist, oom, lam_idx, done);

    // forward FFT of (-1)^n*x -> fhat in scrambled order (4 passes)
    k_tr_fwd_in<<<tg, tb, 0, stream>>>(x, sA);
    k_fft1024<<<1024, 256, 0, stream>>>(sA, sB, -1.0f, 1);
    k_tr_c2c<<<tg, tb, 0, stream>>>(sB, sA);
    k_fft1024<<<1024, 256, 0, stream>>>(sA, fhat, -1.0f, 0);

    // 50 VMD iterations (lam ping-pong; u never materialized)
    for (int n = 0; n < 50; ++n) {
        float2* la = (n & 1) ? lam1 : lam0;   // lam_{n-1}
        float2* lb = (n & 1) ? lam0 : lam1;   // lam_{n-2} in, lam_n out
        const int check = (n > 0 && (n % 10) == 0) ? 1 : 0;
        const int convEval = (n > 1 && ((n - 1) % 10) == 0) ? 1 : 0;
        const float* pPrev = partials + (size_t)((n + 1) & 1) * 8 * NB;
        float* pCur        = partials + (size_t)(n & 1) * 8 * NB;
        k_iter<<<NB, 256, 0, stream>>>(fhat, la, lb, pPrev, pCur,
                                       om_hist, oom, lam_idx, done,
                                       n, check, convEval);
    }

    // inverse FFTs of u_k (u fused into first pass), output (-1)^n*Re(.)/N
    if (batch3) {
        k_fftu<<<3072, 256, 0, stream>>>(fhat, lam0, lam1, lam_idx, oom, sB, 0);
        k_tr_c2c<<<dim3(32, 32, 3), tb, 0, stream>>>(sB, sA);
        k_fft1024<<<3072, 256, 0, stream>>>(sA, sB, 1.0f, 0);
        k_tr_out<<<dim3(32, 32, 3), tb, 0, stream>>>(sB, outp);
    } else {
        for (int k = 0; k < 3; ++k) {
            k_fftu<<<1024, 256, 0, stream>>>(fhat, lam0, lam1, lam_idx, oom, sB, k);
            k_tr_c2c<<<tg, tb, 0, stream>>>(sB, sA);
            k_fft1024<<<1024, 256, 0, stream>>>(sA, sB, 1.0f, 0);
            k_tr_out<<<tg, tb, 0, stream>>>(sB, outp + (size_t)k * TN);
        }
    }
}